// Round 15
// baseline (42.298 us; speedup 1.0000x reference)
//
#include <hip/hip_runtime.h>
#include <math.h>

#define HH 256
#define WW 256
#define EPS2D 1e-4f
#define MAXN 1024
#define CULL_THR 23.0f   // skip gaussian in a row if max alpha on the row < 2^-23
#define NL_HALF_LOG2E -0.72134752044448170368f
#define FLAG_MAGIC 0x5AFE5AFEu

// SoA records, depth-sorted front-to-back (in d_ws):
//   A[g] = (mx, my, qa, qb)   B[g] = (qc, lk, cr, cg)   C[g] = cb
// alpha = exp2( qa*dx*dx + qb*dx*dy + qc*dy*dy + lk ),  qa,qc < 0
//
// Single plain dispatch, 256 blocks x 512 threads (8 waves, 1 block/CU):
//   blocks 0..pblocks-1: prep their 64 gaussians -> A/B/C, fence, set
//   flags[blk]=MAGIC (release). All blocks spin until all flags==MAGIC
//   (acquire), then render their row. No flag reset needed: replays write
//   bitwise-identical A/B/C, so a stale MAGIC only lets a block read values
//   that are already equal to what this replay writes.

__global__ __launch_bounds__(512) void fused_kernel(
    const float* __restrict__ means3D, const float* __restrict__ covs3d,
    const float* __restrict__ colors,  const float* __restrict__ opac,
    const float* __restrict__ Km,      const float* __restrict__ Rm,
    const float* __restrict__ tv,
    float4* __restrict__ A, float4* __restrict__ B, float* __restrict__ C,
    unsigned int* __restrict__ flags,
    float* __restrict__ out, int n, int pblocks)
{
    __shared__ __align__(16) char smem[61440];
    // prep views (first ~21.3 KB; released before render phase)
    float* s_mean  = (float*)smem;                    // 12288 B
    float* s_depth = (float*)(smem + 12288);          //  4096 B
    float* s_cov   = (float*)(smem + 16384);          //  2304 B
    float* s_col   = (float*)(smem + 18688);          //   768 B
    float* s_op    = (float*)(smem + 19456);          //   256 B
    int*   s_pr    = (int*)(smem + 19712);            //  2048 B ([8][64])
    // render views (full 61440 B)
    float4 (*s_p0)[128]   = (float4(*)[128])smem;             // 16384 B
    float4 (*s_p1)[128]   = (float4(*)[128])(smem + 16384);   // 16384 B
    float4 (*s_part)[256] = (float4(*)[256])(smem + 32768);   // 28672 B

    int t = threadIdx.x, lane = t & 63, w = t >> 6;   // w in 0..7
    int blk = blockIdx.x;

    // ================= phase 1: prep (blocks 0..pblocks-1) =================
    if (blk < pblocks) {
        int g0b = blk * 64;
        int nb = n - g0b; if (nb > 64) nb = 64;

        // ---- coalesced staging (stride 512) ----
        {
            int nm4 = (3*n) >> 2;
            const float4* m4 = (const float4*)means3D;
            for (int i = t; i < nm4; i += 512) ((float4*)s_mean)[i] = m4[i];
            for (int i = (nm4<<2) + t; i < 3*n; i += 512) s_mean[i] = means3D[i];

            const float* cbase = covs3d + (size_t)g0b * 9;
            int ncf = nb * 9, nc4 = ncf >> 2;
            for (int i = t; i < nc4; i += 512) ((float4*)s_cov)[i] = ((const float4*)cbase)[i];
            for (int i = (nc4<<2) + t; i < ncf; i += 512) s_cov[i] = cbase[i];

            const float* lbase = colors + (size_t)g0b * 3;
            int nlf = nb * 3, nl4 = nlf >> 2;
            for (int i = t; i < nl4; i += 512) ((float4*)s_col)[i] = ((const float4*)lbase)[i];
            for (int i = (nl4<<2) + t; i < nlf; i += 512) s_col[i] = lbase[i];

            const float* obase = opac + g0b;
            int no4 = nb >> 2;
            for (int i = t; i < no4; i += 512) ((float4*)s_op)[i] = ((const float4*)obase)[i];
            for (int i = (no4<<2) + t; i < nb; i += 512) s_op[i] = obase[i];
        }
        __syncthreads();

        float R00=Rm[0],R01=Rm[1],R02=Rm[2];
        float R10=Rm[3],R11=Rm[4],R12=Rm[5];
        float R20=Rm[6],R21=Rm[7],R22=Rm[8];
        float t0=tv[0], t1=tv[1], t2=tv[2];

        // ---- all depths ----
        for (int g = t; g < MAXN; g += 512) {
            float d = 1e30f;
            if (g < n) {
                float X=s_mean[3*g+0], Y=s_mean[3*g+1], Z=s_mean[3*g+2];
                float cz = R20*X + R21*Y + R22*Z + t2;
                d = fmaxf(cz, 1.0f);
            }
            s_depth[g] = d;
        }
        __syncthreads();

        // ---- projection (wave 0, lane-parallel) ----
        float mx=0.f,my=0.f,qa=0.f,qb=0.f,qc=0.f,lk=0.f,cr=0.f,cg_=0.f,cbv=0.f;
        if (w == 0 && lane < nb) {
            int i = g0b + lane;
            float X = s_mean[3*i+0], Y = s_mean[3*i+1], Z = s_mean[3*i+2];
            float cx = R00*X + R01*Y + R02*Z + t0;
            float cy = R10*X + R11*Y + R12*Z + t1;
            float cz = R20*X + R21*Y + R22*Z + t2;
            float depth = s_depth[i];

            float K00=Km[0],K01=Km[1],K02=Km[2];
            float K10=Km[3],K11=Km[4],K12=Km[5];
            float K20=Km[6],K21=Km[7],K22=Km[8];
            float sx = K00*cx + K01*cy + K02*cz;
            float sy = K10*cx + K11*cy + K12*cz;
            float sz = K20*cx + K21*cy + K22*cz;
            mx = sx / sz;
            my = sy / sz;

            float invz  = 1.0f / cz;
            float invz2 = invz * invz;
            float j00 =  K00 * invz;
            float j02 = -K00 * cx * invz2;
            float j11 =  K11 * invz;
            float j12 = -K11 * cy * invz2;

            const float* S = s_cov + 9*lane;
            float S00=S[0],S01=S[1],S02=S[2];
            float S10=S[3],S11=S[4],S12=S[5];
            float S20=S[6],S21=S[7],S22=S[8];

            float M00 = R00*S00 + R01*S10 + R02*S20;
            float M01 = R00*S01 + R01*S11 + R02*S21;
            float M02 = R00*S02 + R01*S12 + R02*S22;
            float M10 = R10*S00 + R11*S10 + R12*S20;
            float M11 = R10*S01 + R11*S11 + R12*S21;
            float M12 = R10*S02 + R11*S12 + R12*S22;
            float M20 = R20*S00 + R21*S10 + R22*S20;
            float M21 = R20*S01 + R21*S11 + R22*S21;
            float M22 = R20*S02 + R21*S12 + R22*S22;
            float C00 = M00*R00 + M01*R01 + M02*R02;
            float C01 = M00*R10 + M01*R11 + M02*R12;
            float C02 = M00*R20 + M01*R21 + M02*R22;
            float C11 = M10*R10 + M11*R11 + M12*R12;
            float C12 = M10*R20 + M11*R21 + M12*R22;
            float C22 = M20*R20 + M21*R21 + M22*R22;

            float a_ = j00*j00*C00 + 2.0f*j00*j02*C02 + j02*j02*C22 + EPS2D;
            float b_ = j00*j11*C01 + j00*j12*C02 + j02*j11*C12 + j02*j12*C22;
            float c_ = j11*j11*C11 + 2.0f*j11*j12*C12 + j12*j12*C22 + EPS2D;

            float det = a_ * c_ - b_ * b_;
            float ia =  c_ / det;
            float ib = -b_ / det;
            float ic =  a_ / det;
            float norm = 1.0f / (6.283185307179586f * sqrtf(det));

            bool valid = (depth > 1.0f) && (depth < 50.0f);
            float k = s_op[lane] * norm * (valid ? 1.0f : 0.0f);

            qa = NL_HALF_LOG2E * ia;
            qb = 2.0f * NL_HALF_LOG2E * ib;
            qc = NL_HALF_LOG2E * ic;
            lk = log2f(k);
            cr  = s_col[3*lane+0];
            cg_ = s_col[3*lane+1];
            cbv = s_col[3*lane+2];
        }

        // ---- partial rank: wave w scans depth-eighth [128w, 128w+128) ----
        {
            int cnt = 0;
            if (lane < nb) {
                int i = g0b + lane;
                float d = s_depth[i];
                const float4* d4 = (const float4*)s_depth;
                int jb = w * 32;                 // float4 index base
                #pragma unroll 4
                for (int jj = 0; jj < 32; ++jj) {
                    float4 v = d4[jb + jj];       // wave-uniform -> broadcast
                    int j = (jb + jj) << 2;
                    cnt += (v.x < d || (v.x == d && j+0 < i)) ? 1 : 0;
                    cnt += (v.y < d || (v.y == d && j+1 < i)) ? 1 : 0;
                    cnt += (v.z < d || (v.z == d && j+2 < i)) ? 1 : 0;
                    cnt += (v.w < d || (v.w == d && j+3 < i)) ? 1 : 0;
                }
            }
            s_pr[w*64 + lane] = cnt;
        }
        __syncthreads();

        // ---- combine + scatter (wave 0), then signal ----
        if (w == 0 && lane < nb) {
            int rank = 0;
            #pragma unroll
            for (int k = 0; k < 8; ++k) rank += s_pr[k*64 + lane];
            A[rank] = make_float4(mx, my, qa, qb);
            B[rank] = make_float4(qc, lk, cr, cg_);
            C[rank] = cbv;
        }
        __syncthreads();
        if (t == 0) {
            __threadfence();
            __hip_atomic_store(&flags[blk], FLAG_MAGIC, __ATOMIC_RELEASE,
                               __HIP_MEMORY_SCOPE_AGENT);
        }
    }

    // ================= barrier: wait for all prep blocks =================
    if (t == 0) {
        for (int b = 0; b < pblocks; ++b) {
            while (__hip_atomic_load(&flags[b], __ATOMIC_ACQUIRE,
                                     __HIP_MEMORY_SCOPE_AGENT) != FLAG_MAGIC) {
                __builtin_amdgcn_s_sleep(2);
            }
        }
    }
    __syncthreads();   // releases prep LDS region, orders A/B/C reads

    // ================= phase 2: render own row =================
    int row = blk;
    int q0 = (n *  w     ) >> 3;
    int q1 = (n * (w + 1)) >> 3;
    float pyf = (float)row;

    // ---- pipelined exact-interval cull + fold -> per-wave LDS lists ----
    int cnt = 0;
    if (q1 > q0) {
        int jc = min(q0 + lane, q1 - 1);
        float4 a = A[jc];
        float4 b = B[jc];
        float  c = C[jc];
        for (int ch = q0; ch < q1; ch += 64) {
            float4 a_n, b_n; float c_n;
            int cn = ch + 64;
            if (cn < q1) {
                int jc2 = min(cn + lane, q1 - 1);
                a_n = A[jc2];
                b_n = B[jc2];
                c_n = C[jc2];
            }
            int jj = ch + lane;
            bool keep = false;
            float qbdy = 0.f, u = 0.f;
            if (jj < q1) {
                float dy = pyf - a.y;
                qbdy = a.w * dy;
                u    = fmaf(b.x * dy, dy, b.y);       // qc*dy^2 + lk
                float disc = fmaf(qbdy, qbdy, -4.0f * a.z * (u + CULL_THR));
                if (disc > 0.0f) {
                    float inv2qa = 0.5f / a.z;            // negative
                    float shw = sqrtf(disc) * inv2qa;     // <= 0
                    float ctr = -qbdy * inv2qa;
                    float xl = a.x + ctr + shw;
                    float xr = a.x + ctr - shw;
                    keep = (xr >= 0.0f) && (xl <= 255.0f);
                }
            }
            unsigned long long mk = __ballot(keep);
            int pre = __popcll(mk & ((1ull << lane) - 1ull));
            if (keep) {
                int pos = cnt + pre;
                s_p0[w][pos] = make_float4(a.x, a.z, qbdy, u);
                s_p1[w][pos] = make_float4(b.z, b.w, c, 0.f);
            }
            cnt += __popcll(mk);
            a = a_n; b = b_n; c = c_n;
        }
    }

    // ---- composite own eighth-list, 4 px/thread ----
    float lanef = (float)lane;
    float T0=1.f,T1=1.f,T2=1.f,T3=1.f;
    float r0=0.f,g0=0.f,b0=0.f, r1=0.f,g1=0.f,b1=0.f;
    float r2=0.f,g2=0.f,b2=0.f, r3=0.f,g3=0.f,b3=0.f;

    for (int k = 0; k < cnt; ++k) {
        float4 p0 = s_p0[w][k];
        float4 p1 = s_p1[w][k];
        float dx = lanef - p0.x;
        {
            float q = fmaf(fmaf(p0.y, dx, p0.z), dx, p0.w);
            float wg = T0 * __builtin_amdgcn_exp2f(q);
            r0 = fmaf(wg, p1.x, r0); g0 = fmaf(wg, p1.y, g0);
            b0 = fmaf(wg, p1.z, b0); T0 -= wg;
        }
        dx += 64.0f;
        {
            float q = fmaf(fmaf(p0.y, dx, p0.z), dx, p0.w);
            float wg = T1 * __builtin_amdgcn_exp2f(q);
            r1 = fmaf(wg, p1.x, r1); g1 = fmaf(wg, p1.y, g1);
            b1 = fmaf(wg, p1.z, b1); T1 -= wg;
        }
        dx += 64.0f;
        {
            float q = fmaf(fmaf(p0.y, dx, p0.z), dx, p0.w);
            float wg = T2 * __builtin_amdgcn_exp2f(q);
            r2 = fmaf(wg, p1.x, r2); g2 = fmaf(wg, p1.y, g2);
            b2 = fmaf(wg, p1.z, b2); T2 -= wg;
        }
        dx += 64.0f;
        {
            float q = fmaf(fmaf(p0.y, dx, p0.z), dx, p0.w);
            float wg = T3 * __builtin_amdgcn_exp2f(q);
            r3 = fmaf(wg, p1.x, r3); g3 = fmaf(wg, p1.y, g3);
            b3 = fmaf(wg, p1.z, b3); T3 -= wg;
        }
    }

    // ---- merge eighths: final = P0 . P1 . ... . P7 ----
    if (w != 0) {
        s_part[w-1][lane +   0] = make_float4(r0, g0, b0, T0);
        s_part[w-1][lane +  64] = make_float4(r1, g1, b1, T1);
        s_part[w-1][lane + 128] = make_float4(r2, g2, b2, T2);
        s_part[w-1][lane + 192] = make_float4(r3, g3, b3, T3);
    }
    __syncthreads();
    if (w == 0) {
        float rr[4]  = {r0, r1, r2, r3};
        float gg[4]  = {g0, g1, g2, g3};
        float bbv[4] = {b0, b1, b2, b3};
        float tt[4]  = {T0, T1, T2, T3};
        #pragma unroll
        for (int i = 0; i < 4; ++i) {
            int px = lane + (i << 6);
            float4 m = s_part[6][px];
            float ar = m.x, ag = m.y, ab = m.z;
            #pragma unroll
            for (int s = 5; s >= 0; --s) {
                float4 ms = s_part[s][px];
                ar = fmaf(ms.w, ar, ms.x);
                ag = fmaf(ms.w, ag, ms.y);
                ab = fmaf(ms.w, ab, ms.z);
            }
            float cr = fmaf(tt[i], ar, rr[i]);
            float cg = fmaf(tt[i], ag, gg[i]);
            float cb = fmaf(tt[i], ab, bbv[i]);
            int p = row * 256 + px;
            out[3*p+0] = cr;
            out[3*p+1] = cg;
            out[3*p+2] = cb;
        }
    }
}

extern "C" void kernel_launch(void* const* d_in, const int* in_sizes, int n_in,
                              void* d_out, int out_size, void* d_ws, size_t ws_size,
                              hipStream_t stream)
{
    const float* means3D = (const float*)d_in[0];
    const float* covs3d  = (const float*)d_in[1];
    const float* colors  = (const float*)d_in[2];
    const float* opac    = (const float*)d_in[3];
    const float* Km      = (const float*)d_in[4];
    const float* Rm      = (const float*)d_in[5];
    const float* tv      = (const float*)d_in[6];
    int n = in_sizes[3];
    if (n > MAXN) n = MAXN;

    float4* A = (float4*)d_ws;                          // 16 KB
    float4* B = (float4*)((char*)d_ws + 16384);         // 16 KB
    float*  C = (float*)((char*)d_ws + 32768);          // 4 KB
    unsigned int* flags = (unsigned int*)((char*)d_ws + 36864);

    int pblocks = (n + 63) / 64;

    hipLaunchKernelGGL(fused_kernel, dim3(HH), dim3(512), 0, stream,
                       means3D, covs3d, colors, opac, Km, Rm, tv,
                       A, B, C, flags, (float*)d_out, n, pblocks);
}

// Round 16
// 21.585 us; speedup vs baseline: 1.9596x; 1.9596x over previous
//
#include <hip/hip_runtime.h>
#include <math.h>

#define HH 256
#define WW 256
#define EPS2D 1e-4f
#define MAXN 1024
#define CULL_THR 23.0f   // skip gaussian in a row if max alpha on the row < 2^-23
#define NL_HALF_LOG2E -0.72134752044448170368f

// SoA records, depth-sorted front-to-back (in d_ws):
//   A[g] = (mx, my, qa, qb)   B[g] = (qc, lk, cr, cg)   C[g] = cb
// alpha = exp2( qa*dx*dx + qb*dx*dy + qc*dy*dy + lk ),  qa,qc < 0

// prep: grid = ceil(n/64) blocks x 256 threads (4 waves).
// Block b owns gaussians [64b, 64b+64). Wave w computes partial ranks over
// depth quarter [256w, 256w+256); wave 0 does projection lane-parallel.
__global__ __launch_bounds__(256) void prep_kernel(
    const float* __restrict__ means3D, const float* __restrict__ covs3d,
    const float* __restrict__ colors,  const float* __restrict__ opac,
    const float* __restrict__ Km,      const float* __restrict__ Rm,
    const float* __restrict__ tv,
    float4* __restrict__ A, float4* __restrict__ B, float* __restrict__ C,
    int n)
{
    __shared__ float s_mean[MAXN*3];   // all means (12 KB)
    __shared__ float s_depth[MAXN];    // all depths (4 KB)
    __shared__ float s_cov[64*9];
    __shared__ float s_col[64*3];
    __shared__ float s_op[64];
    __shared__ int   s_pr[4][64];

    int t = threadIdx.x, lane = t & 63, w = t >> 6;
    int g0b = blockIdx.x * 64;
    int nb = n - g0b; if (nb > 64) nb = 64; if (nb < 0) nb = 0;

    // ---- coalesced staging ----
    {
        int nm4 = (3*n) >> 2;
        const float4* m4 = (const float4*)means3D;
        for (int i = t; i < nm4; i += 256) ((float4*)s_mean)[i] = m4[i];
        for (int i = (nm4<<2) + t; i < 3*n; i += 256) s_mean[i] = means3D[i];

        const float* cbase = covs3d + (size_t)g0b * 9;
        int ncf = nb * 9, nc4 = ncf >> 2;
        for (int i = t; i < nc4; i += 256) ((float4*)s_cov)[i] = ((const float4*)cbase)[i];
        for (int i = (nc4<<2) + t; i < ncf; i += 256) s_cov[i] = cbase[i];

        const float* lbase = colors + (size_t)g0b * 3;
        int nlf = nb * 3, nl4 = nlf >> 2;
        for (int i = t; i < nl4; i += 256) ((float4*)s_col)[i] = ((const float4*)lbase)[i];
        for (int i = (nl4<<2) + t; i < nlf; i += 256) s_col[i] = lbase[i];

        const float* obase = opac + g0b;
        int no4 = nb >> 2;
        for (int i = t; i < no4; i += 256) ((float4*)s_op)[i] = ((const float4*)obase)[i];
        for (int i = (no4<<2) + t; i < nb; i += 256) s_op[i] = obase[i];
    }
    __syncthreads();

    float R00=Rm[0],R01=Rm[1],R02=Rm[2];
    float R10=Rm[3],R11=Rm[4],R12=Rm[5];
    float R20=Rm[6],R21=Rm[7],R22=Rm[8];
    float t0=tv[0], t1=tv[1], t2=tv[2];

    // ---- all depths ----
    for (int g = t; g < MAXN; g += 256) {
        float d = 1e30f;
        if (g < n) {
            float X=s_mean[3*g+0], Y=s_mean[3*g+1], Z=s_mean[3*g+2];
            float cz = R20*X + R21*Y + R22*Z + t2;
            d = fmaxf(cz, 1.0f);
        }
        s_depth[g] = d;
    }
    __syncthreads();

    // ---- projection (wave 0, lane-parallel; waves 1-3 fall through to rank) ----
    float mx=0.f,my=0.f,qa=0.f,qb=0.f,qc=0.f,lk=0.f,cr=0.f,cg=0.f,cbv=0.f;
    if (w == 0 && lane < nb) {
        int i = g0b + lane;
        float X = s_mean[3*i+0], Y = s_mean[3*i+1], Z = s_mean[3*i+2];
        float cx = R00*X + R01*Y + R02*Z + t0;
        float cy = R10*X + R11*Y + R12*Z + t1;
        float cz = R20*X + R21*Y + R22*Z + t2;
        float depth = s_depth[i];

        float K00=Km[0],K01=Km[1],K02=Km[2];
        float K10=Km[3],K11=Km[4],K12=Km[5];
        float K20=Km[6],K21=Km[7],K22=Km[8];
        float sx = K00*cx + K01*cy + K02*cz;
        float sy = K10*cx + K11*cy + K12*cz;
        float sz = K20*cx + K21*cy + K22*cz;
        mx = sx / sz;
        my = sy / sz;

        float invz  = 1.0f / cz;
        float invz2 = invz * invz;
        float j00 =  K00 * invz;
        float j02 = -K00 * cx * invz2;
        float j11 =  K11 * invz;
        float j12 = -K11 * cy * invz2;

        const float* S = s_cov + 9*lane;
        float S00=S[0],S01=S[1],S02=S[2];
        float S10=S[3],S11=S[4],S12=S[5];
        float S20=S[6],S21=S[7],S22=S[8];

        float M00 = R00*S00 + R01*S10 + R02*S20;
        float M01 = R00*S01 + R01*S11 + R02*S21;
        float M02 = R00*S02 + R01*S12 + R02*S22;
        float M10 = R10*S00 + R11*S10 + R12*S20;
        float M11 = R10*S01 + R11*S11 + R12*S21;
        float M12 = R10*S02 + R11*S12 + R12*S22;
        float M20 = R20*S00 + R21*S10 + R22*S20;
        float M21 = R20*S01 + R21*S11 + R22*S21;
        float M22 = R20*S02 + R21*S12 + R22*S22;
        float C00 = M00*R00 + M01*R01 + M02*R02;
        float C01 = M00*R10 + M01*R11 + M02*R12;
        float C02 = M00*R20 + M01*R21 + M02*R22;
        float C11 = M10*R10 + M11*R11 + M12*R12;
        float C12 = M10*R20 + M11*R21 + M12*R22;
        float C22 = M20*R20 + M21*R21 + M22*R22;

        float a_ = j00*j00*C00 + 2.0f*j00*j02*C02 + j02*j02*C22 + EPS2D;
        float b_ = j00*j11*C01 + j00*j12*C02 + j02*j11*C12 + j02*j12*C22;
        float c_ = j11*j11*C11 + 2.0f*j11*j12*C12 + j12*j12*C22 + EPS2D;

        float det = a_ * c_ - b_ * b_;
        float ia =  c_ / det;
        float ib = -b_ / det;
        float ic =  a_ / det;
        float norm = 1.0f / (6.283185307179586f * sqrtf(det));

        bool valid = (depth > 1.0f) && (depth < 50.0f);
        float k = s_op[lane] * norm * (valid ? 1.0f : 0.0f);

        qa = NL_HALF_LOG2E * ia;
        qb = 2.0f * NL_HALF_LOG2E * ib;
        qc = NL_HALF_LOG2E * ic;
        lk = log2f(k);
        cr = s_col[3*lane+0];
        cg = s_col[3*lane+1];
        cbv = s_col[3*lane+2];
    }

    // ---- partial rank: wave w scans depth quarter [256w, 256w+256) ----
    {
        int cnt = 0;
        if (lane < nb) {
            int i = g0b + lane;
            float d = s_depth[i];
            const float4* d4 = (const float4*)s_depth;
            int jb = w * 64;                 // float4 index base
            #pragma unroll 4
            for (int jj = 0; jj < 64; ++jj) {
                float4 v = d4[jb + jj];       // wave-uniform -> broadcast
                int j = (jb + jj) << 2;
                cnt += (v.x < d || (v.x == d && j+0 < i)) ? 1 : 0;
                cnt += (v.y < d || (v.y == d && j+1 < i)) ? 1 : 0;
                cnt += (v.z < d || (v.z == d && j+2 < i)) ? 1 : 0;
                cnt += (v.w < d || (v.w == d && j+3 < i)) ? 1 : 0;
            }
        }
        s_pr[w][lane] = cnt;
    }
    __syncthreads();

    // ---- combine + scatter (wave 0) ----
    if (w == 0 && lane < nb) {
        int rank = s_pr[0][lane] + s_pr[1][lane] + s_pr[2][lane] + s_pr[3][lane];
        A[rank] = make_float4(mx, my, qa, qb);
        B[rank] = make_float4(qc, lk, cr, cg);
        C[rank] = cbv;
    }
}

// Render: grid = 256 blocks (one per row), 512 threads = 8 waves.
// wave w handles depth-eighth [n*w/8, n*(w+1)/8) over the FULL row,
// 4 px/thread. Pipelined EXACT x-interval cull writes row-folded params
// straight into per-wave LDS lists. One barrier, wave 0 merges 8 partials.
__global__ __launch_bounds__(512) void render_kernel(
    const float4* __restrict__ A, const float4* __restrict__ B,
    const float* __restrict__ C, float* __restrict__ out, int n)
{
    __shared__ float4 s_p0[8][128];    // 16 KB
    __shared__ float4 s_p1[8][128];    // 16 KB
    __shared__ float4 s_part[7][256];  // 28 KB

    int t = threadIdx.x, lane = t & 63, w = t >> 6;   // w in 0..7
    int row = blockIdx.x;
    int q0 = (n *  w     ) >> 3;
    int q1 = (n * (w + 1)) >> 3;
    float pyf = (float)row;

    // ---- pipelined exact-interval cull + fold -> LDS lists ----
    int cnt = 0;
    if (q1 > q0) {
        int jc = min(q0 + lane, q1 - 1);
        float4 a = A[jc];
        float4 b = B[jc];
        float  c = C[jc];
        for (int ch = q0; ch < q1; ch += 64) {
            float4 a_n, b_n; float c_n;
            int cn = ch + 64;
            if (cn < q1) {
                int jc2 = min(cn + lane, q1 - 1);
                a_n = A[jc2];
                b_n = B[jc2];
                c_n = C[jc2];
            }
            int jj = ch + lane;
            bool keep = false;
            float qbdy = 0.f, u = 0.f;
            if (jj < q1) {
                float dy = pyf - a.y;
                qbdy = a.w * dy;
                u    = fmaf(b.x * dy, dy, b.y);       // qc*dy^2 + lk
                // keep iff exists x in [0,255] with q(x) >= -THR
                float disc = fmaf(qbdy, qbdy, -4.0f * a.z * (u + CULL_THR));
                if (disc > 0.0f) {
                    float inv2qa = 0.5f / a.z;            // negative
                    float shw = sqrtf(disc) * inv2qa;     // <= 0
                    float ctr = -qbdy * inv2qa;
                    float xl = a.x + ctr + shw;
                    float xr = a.x + ctr - shw;
                    keep = (xr >= 0.0f) && (xl <= 255.0f);
                }
            }
            unsigned long long mk = __ballot(keep);
            int pre = __popcll(mk & ((1ull << lane) - 1ull));
            if (keep) {
                int pos = cnt + pre;
                s_p0[w][pos] = make_float4(a.x, a.z, qbdy, u);
                s_p1[w][pos] = make_float4(b.z, b.w, c, 0.f);
            }
            cnt += __popcll(mk);
            a = a_n; b = b_n; c = c_n;
        }
    }

    // ---- composite own eighth-list, 4 px/thread ----
    float lanef = (float)lane;
    float T0=1.f,T1=1.f,T2=1.f,T3=1.f;
    float r0=0.f,g0=0.f,b0=0.f, r1=0.f,g1=0.f,b1=0.f;
    float r2=0.f,g2=0.f,b2=0.f, r3=0.f,g3=0.f,b3=0.f;

    for (int k = 0; k < cnt; ++k) {
        float4 p0 = s_p0[w][k];
        float4 p1 = s_p1[w][k];
        float dx = lanef - p0.x;
        {
            float q = fmaf(fmaf(p0.y, dx, p0.z), dx, p0.w);
            float wg = T0 * __builtin_amdgcn_exp2f(q);
            r0 = fmaf(wg, p1.x, r0); g0 = fmaf(wg, p1.y, g0);
            b0 = fmaf(wg, p1.z, b0); T0 -= wg;
        }
        dx += 64.0f;
        {
            float q = fmaf(fmaf(p0.y, dx, p0.z), dx, p0.w);
            float wg = T1 * __builtin_amdgcn_exp2f(q);
            r1 = fmaf(wg, p1.x, r1); g1 = fmaf(wg, p1.y, g1);
            b1 = fmaf(wg, p1.z, b1); T1 -= wg;
        }
        dx += 64.0f;
        {
            float q = fmaf(fmaf(p0.y, dx, p0.z), dx, p0.w);
            float wg = T2 * __builtin_amdgcn_exp2f(q);
            r2 = fmaf(wg, p1.x, r2); g2 = fmaf(wg, p1.y, g2);
            b2 = fmaf(wg, p1.z, b2); T2 -= wg;
        }
        dx += 64.0f;
        {
            float q = fmaf(fmaf(p0.y, dx, p0.z), dx, p0.w);
            float wg = T3 * __builtin_amdgcn_exp2f(q);
            r3 = fmaf(wg, p1.x, r3); g3 = fmaf(wg, p1.y, g3);
            b3 = fmaf(wg, p1.z, b3); T3 -= wg;
        }
    }

    // ---- merge eighths: final = P0 . P1 . ... . P7 ----
    if (w != 0) {
        s_part[w-1][lane +   0] = make_float4(r0, g0, b0, T0);
        s_part[w-1][lane +  64] = make_float4(r1, g1, b1, T1);
        s_part[w-1][lane + 128] = make_float4(r2, g2, b2, T2);
        s_part[w-1][lane + 192] = make_float4(r3, g3, b3, T3);
    }
    __syncthreads();
    if (w == 0) {
        float rr[4]  = {r0, r1, r2, r3};
        float gg[4]  = {g0, g1, g2, g3};
        float bbv[4] = {b0, b1, b2, b3};
        float tt[4]  = {T0, T1, T2, T3};
        #pragma unroll
        for (int i = 0; i < 4; ++i) {
            int px = lane + (i << 6);
            // back-to-front accumulate partials P1..P7 (indices 0..6)
            float4 m = s_part[6][px];
            float ar = m.x, ag = m.y, ab = m.z;
            #pragma unroll
            for (int s = 5; s >= 0; --s) {
                float4 ms = s_part[s][px];
                ar = fmaf(ms.w, ar, ms.x);
                ag = fmaf(ms.w, ag, ms.y);
                ab = fmaf(ms.w, ab, ms.z);
            }
            float cr = fmaf(tt[i], ar, rr[i]);
            float cg = fmaf(tt[i], ag, gg[i]);
            float cb = fmaf(tt[i], ab, bbv[i]);
            int p = row * 256 + px;
            out[3*p+0] = cr;
            out[3*p+1] = cg;
            out[3*p+2] = cb;
        }
    }
}

extern "C" void kernel_launch(void* const* d_in, const int* in_sizes, int n_in,
                              void* d_out, int out_size, void* d_ws, size_t ws_size,
                              hipStream_t stream)
{
    const float* means3D = (const float*)d_in[0];
    const float* covs3d  = (const float*)d_in[1];
    const float* colors  = (const float*)d_in[2];
    const float* opac    = (const float*)d_in[3];
    const float* Km      = (const float*)d_in[4];
    const float* Rm      = (const float*)d_in[5];
    const float* tv      = (const float*)d_in[6];
    int n = in_sizes[3];
    if (n > MAXN) n = MAXN;

    float4* A = (float4*)d_ws;                          // 16 KB
    float4* B = (float4*)((char*)d_ws + 16384);         // 16 KB
    float*  C = (float*)((char*)d_ws + 32768);          // 4 KB

    int pblocks = (n + 63) / 64;
    hipLaunchKernelGGL(prep_kernel, dim3(pblocks), dim3(256), 0, stream,
                       means3D, covs3d, colors, opac, Km, Rm, tv, A, B, C, n);

    hipLaunchKernelGGL(render_kernel, dim3(HH), dim3(512), 0, stream,
                       A, B, C, (float*)d_out, n);
}